// Round 1
// 697.208 us; speedup vs baseline: 1.0721x; 1.0721x over previous
//
#include <hip/hip_runtime.h>
#include <hip/hip_bf16.h>

// GCN 2-layer fused:  out = A·A·(x @ (W1@W2)) + (A·1)⊗(b1@W2) + b2
// A = D^-1/2 (Adj + I) D^-1/2.  Aggregation is CSR gather (no fp32 atomics):
//   out[d] = dinv[d]*( sum_{s->d} dinv[s]*F[s] + dinv[d]*F[d] )
// Runtime-detects float dtype (f32 vs bf16) and edge dtype (int32 vs int64).
//
// R1 changes vs baseline (latency-bound k_gemm @15% occupancy, all pipes idle):
//  - k_gemm: 16 rows/wave (was 32) -> 2x waves; B packed [ks][nc][lane] so each
//    fragment load is one coalesced 1KB wave transaction (was 16B @ 1KB stride).
//  - k_gather: split-wave (2 edges in flight, float4/lane) -> 2x MLP, 16B loads.
//  - k_dinv fused into k_scan1.

typedef __attribute__((ext_vector_type(8))) short short8;   // 8 bf16 (4 VGPRs)
typedef __attribute__((ext_vector_type(4))) float f32x4;

#define DIN 512
#define DOUT 128

__device__ inline short f2bs(float f) {
    __hip_bfloat16 h = __float2bfloat16(f);
    return __builtin_bit_cast(short, h);
}
__device__ inline float b2f(const void* p, long long idx) {
    return __bfloat162float(((const __hip_bfloat16*)p)[idx]);
}
__device__ inline int edge_at(const void* ei, int eflag, long long idx) {
    return eflag ? ((const int*)ei)[idx] : (int)((const long long*)ei)[idx];
}

// ---- float dtype detect on x: bf16 data -> ~100% of uint16s have N(0,1)-plausible
//      exponents; f32 data -> low-mantissa halves are uniform -> ~56%.  fflag=1 => bf16.
__global__ void k_fdetect(const unsigned short* __restrict__ xr, int* __restrict__ fflag) {
    __shared__ int cnt;
    if (threadIdx.x == 0) cnt = 0;
    __syncthreads();
    int local = 0;
    for (int i = threadIdx.x; i < 8192; i += 256) {
        unsigned e = (xr[i] >> 7) & 0xFF;
        if (e == 0 || (e >= 0x70 && e <= 0x8E)) local++;
    }
    atomicAdd(&cnt, local);
    __syncthreads();
    if (threadIdx.x == 0) *fflag = (cnt >= 7373) ? 1 : 0;   // >=90% plausible => bf16
}

// ---- edge dtype detect: odd int32 words of int64 node ids are all zero.  eflag=1 => int32.
__global__ void k_edetect(const int* __restrict__ ei_raw, int* __restrict__ eflag) {
    __shared__ int any;
    if (threadIdx.x == 0) any = 0;
    __syncthreads();
    for (int i = threadIdx.x; i < 4096; i += 256)
        if (ei_raw[2 * i + 1] != 0) any = 1;   // benign race
    __syncthreads();
    if (threadIdx.x == 0) *eflag = any;
}

// ---- W12 = W1@W2 packed for coalesced MFMA B-fragment loads:
//      w12p[((ks*8+nc)*64 + quad*16 + m16)*8 + jj] = W12[k=ks*32+quad*8+jj][col=nc*16+m16]
__global__ __launch_bounds__(256) void k_w12(const void* __restrict__ W1,
                                             const void* __restrict__ W2,
                                             const int* __restrict__ fflag,
                                             __hip_bfloat16* __restrict__ w12p) {
    int t = blockIdx.x * 256 + threadIdx.x;      // [0, 512*128)
    int d = t >> 7, j = t & 127;                 // d = k index, j = output col
    float acc = 0.f;
    if (*fflag) {
        for (int c = 0; c < 512; ++c)
            acc += b2f(W1, d * 512 + c) * b2f(W2, c * 128 + j);
    } else {
        const float* w1 = (const float*)W1;
        const float* w2 = (const float*)W2;
        for (int c = 0; c < 512; ++c)
            acc += w1[d * 512 + c] * w2[c * 128 + j];
    }
    int ks = d >> 5, r = d & 31;
    int quad = r >> 3, jj = r & 7;
    int nc = j >> 4, m16 = j & 15;
    w12p[(((size_t)(ks * 8 + nc) * 64) + quad * 16 + m16) * 8 + jj] = __float2bfloat16(acc);
}

// ---- b12[j] = sum_c b1[c] * W2[c,j]  (fp32)
__global__ void k_b12(const void* __restrict__ b1, const void* __restrict__ W2,
                      const int* __restrict__ fflag, float* __restrict__ b12) {
    int j = threadIdx.x;                         // 128 threads
    float acc = 0.f;
    if (*fflag) {
        for (int c = 0; c < 512; ++c)
            acc += b2f(b1, c) * b2f(W2, c * 128 + j);
    } else {
        const float* bb = (const float*)b1;
        const float* w2 = (const float*)W2;
        for (int c = 0; c < 512; ++c)
            acc += bb[c] * w2[c * 128 + j];
    }
    b12[j] = acc;
}

// ---- in-degree over dst (real edges; self-loop added analytically)
__global__ __launch_bounds__(256) void k_deg(const void* __restrict__ ei,
                                             const int* __restrict__ eflag, int E,
                                             int* __restrict__ degi) {
    int e = blockIdx.x * 256 + threadIdx.x;
    if (e >= E) return;
    atomicAdd(&degi[edge_at(ei, *eflag, (long long)E + e)], 1);
}

// ---- exclusive scan over degi -> row_ptr (3-kernel two-level scan); dinv fused here
__global__ __launch_bounds__(256) void k_scan1(const int* __restrict__ degi,
                                               int* __restrict__ row_ptr,
                                               int* __restrict__ blocksum,
                                               float* __restrict__ dinv, int n) {
    __shared__ int sh[256];
    int t = threadIdx.x, g = blockIdx.x * 256 + t;
    int val = (g < n) ? degi[g] : 0;
    if (g < n) dinv[g] = rsqrtf((float)(val + 1));    // +1: self-loop
    sh[t] = val;
    __syncthreads();
    for (int o = 1; o < 256; o <<= 1) {
        int v = (t >= o) ? sh[t - o] : 0;
        __syncthreads();
        if (t >= o) sh[t] += v;
        __syncthreads();
    }
    if (g < n) row_ptr[g] = sh[t] - val;         // exclusive within block
    if (t == 255) blocksum[blockIdx.x] = sh[255];
}

__global__ void k_scan2(int* __restrict__ blocksum, int nb) {
    __shared__ int sh[512];
    int t = threadIdx.x;
    int val = (t < nb) ? blocksum[t] : 0;
    sh[t] = val;
    __syncthreads();
    for (int o = 1; o < 512; o <<= 1) {
        int v = (t >= o) ? sh[t - o] : 0;
        __syncthreads();
        if (t >= o) sh[t] += v;
        __syncthreads();
    }
    if (t < nb) blocksum[t] = sh[t] - val;       // exclusive
}

__global__ __launch_bounds__(256) void k_scan3(int* __restrict__ row_ptr,
                                               int* __restrict__ cursor,
                                               const int* __restrict__ blocksum,
                                               int n, int E) {
    int g = blockIdx.x * 256 + threadIdx.x;
    if (g == 0) row_ptr[n] = E;
    if (g >= n) return;
    int v = row_ptr[g] + blocksum[blockIdx.x];
    row_ptr[g] = v;
    cursor[g] = v;
}

// ---- CSR fill: csr[pos] = (src, dinv[src]) bucketed by dst (order arbitrary)
__global__ __launch_bounds__(256) void k_fill(const void* __restrict__ ei,
                                              const int* __restrict__ eflag, int E,
                                              const float* __restrict__ dinv,
                                              int* __restrict__ cursor,
                                              int2* __restrict__ csr) {
    int e = blockIdx.x * 256 + threadIdx.x;
    if (e >= E) return;
    int f = *eflag;
    int s = edge_at(ei, f, e);
    int d = edge_at(ei, f, (long long)E + e);
    int pos = atomicAdd(&cursor[d], 1);
    csr[pos] = make_int2(s, __float_as_int(dinv[s]));
}

// ---- M = x @ W12   (bf16 MFMA, fp32 out).  One wave: 16 rows x 128 cols.
//      B fragments from packed w12p: one coalesced 1KB load per (ks,nc).
__global__ __launch_bounds__(256) void k_gemm(const void* __restrict__ xv,
                                              const short* __restrict__ w12p,
                                              const int* __restrict__ fflag,
                                              float* __restrict__ M, int n) {
    int wave = (blockIdx.x * 256 + threadIdx.x) >> 6;
    int lane = threadIdx.x & 63;
    int row0 = wave * 16;
    if (row0 >= n) return;
    int quad = lane >> 4, m16 = lane & 15;
    const short8* Bp = (const short8*)w12p;      // index: (ks*8+nc)*64 + lane

    f32x4 acc[8];
#pragma unroll
    for (int j = 0; j < 8; ++j) acc[j] = (f32x4){0.f, 0.f, 0.f, 0.f};

    int ra = row0 + m16;
    if (ra >= n) ra = n - 1;                     // tail-safe (reads only)

    if (*fflag) {            // ---- bf16 input path
        const short* xs = (const short*)xv;
#pragma unroll 4
        for (int ks = 0; ks < 16; ++ks) {
            int k0 = ks * 32 + quad * 8;
            short8 A0 = *(const short8*)(xs + (size_t)ra * 512 + k0);
#pragma unroll
            for (int nc = 0; nc < 8; ++nc) {
                short8 B = Bp[(ks * 8 + nc) * 64 + lane];
                acc[nc] = __builtin_amdgcn_mfma_f32_16x16x32_bf16(A0, B, acc[nc], 0, 0, 0);
            }
        }
    } else {                 // ---- f32 input path: load f32, cvt to bf16 fragments
        const float* xf = (const float*)xv;
#pragma unroll 4
        for (int ks = 0; ks < 16; ++ks) {
            int k0 = ks * 32 + quad * 8;
            float4 u0 = *(const float4*)(xf + (size_t)ra * 512 + k0);
            float4 u1 = *(const float4*)(xf + (size_t)ra * 512 + k0 + 4);
            short8 A0;
            A0[0] = f2bs(u0.x); A0[1] = f2bs(u0.y); A0[2] = f2bs(u0.z); A0[3] = f2bs(u0.w);
            A0[4] = f2bs(u1.x); A0[5] = f2bs(u1.y); A0[6] = f2bs(u1.z); A0[7] = f2bs(u1.w);
#pragma unroll
            for (int nc = 0; nc < 8; ++nc) {
                short8 B = Bp[(ks * 8 + nc) * 64 + lane];
                acc[nc] = __builtin_amdgcn_mfma_f32_16x16x32_bf16(A0, B, acc[nc], 0, 0, 0);
            }
        }
    }
    // C/D: col = lane&15, row = quad*4 + reg
#pragma unroll
    for (int nc = 0; nc < 8; ++nc)
#pragma unroll
        for (int r = 0; r < 4; ++r) {
            int row = row0 + quad * 4 + r;
            if (row < n)
                M[(size_t)row * 128 + nc * 16 + m16] = acc[nc][r];
        }
}

// ---- CSR gather: one wave per node; split-wave: half-wave (32 lanes x float4)
//      per edge, halves walk even/odd edges concurrently -> 2x MLP, 16B loads.
//      FINAL=false: dstf[d] = dinv[d]*(sum + dinv[d]*src[d])
//      FINAL=true : fused epilogue  out = acc + dinv[d]*(wsum+dinv[d])*b12 + b2
template <bool FINAL>
__global__ __launch_bounds__(256) void k_gather(const int* __restrict__ row_ptr,
                                                const int2* __restrict__ csr,
                                                const float* __restrict__ dinv,
                                                const float* __restrict__ src_feat,
                                                float* __restrict__ dstf,
                                                const float* __restrict__ b12,
                                                const void* __restrict__ b2,
                                                const int* __restrict__ fflag,
                                                void* __restrict__ out, int n) {
    int d = blockIdx.x * 4 + (threadIdx.x >> 6);
    if (d >= n) return;
    int lane = threadIdx.x & 63;
    int half = lane >> 5, sl = lane & 31;
    int c = sl * 4;
    float di = dinv[d];
    float ax = 0.f, ay = 0.f, az = 0.f, aw = 0.f, wsum = 0.f;
    if (half == 0) {
        float4 s = *(const float4*)(src_feat + (size_t)d * 128 + c);
        ax = di * s.x; ay = di * s.y; az = di * s.z; aw = di * s.w;
    }
    int beg = row_ptr[d], end = row_ptr[d + 1];
    for (int e = beg + half; e < end; e += 2) {
        int2 rec = csr[e];                       // half-wave-uniform broadcast load
        float w = __int_as_float(rec.y);
        float4 v = *(const float4*)(src_feat + (size_t)rec.x * 128 + c);
        ax += w * v.x; ay += w * v.y; az += w * v.z; aw += w * v.w;
        wsum += w;
    }
    // combine the two halves (lane i <-> lane i+32)
    ax += __shfl_xor(ax, 32);
    ay += __shfl_xor(ay, 32);
    az += __shfl_xor(az, 32);
    aw += __shfl_xor(aw, 32);
    wsum += __shfl_xor(wsum, 32);
    if (half) return;
    ax *= di; ay *= di; az *= di; aw *= di;
    if (!FINAL) {
        *(float4*)(dstf + (size_t)d * 128 + c) = make_float4(ax, ay, az, aw);
    } else {
        float coef = di * (wsum + di);
        float o0 = ax + coef * b12[c];
        float o1 = ay + coef * b12[c + 1];
        float o2 = az + coef * b12[c + 2];
        float o3 = aw + coef * b12[c + 3];
        if (*fflag) {
            o0 += b2f(b2, c);     o1 += b2f(b2, c + 1);
            o2 += b2f(b2, c + 2); o3 += b2f(b2, c + 3);
            ushort4 u = make_ushort4((unsigned short)f2bs(o0), (unsigned short)f2bs(o1),
                                     (unsigned short)f2bs(o2), (unsigned short)f2bs(o3));
            *(ushort4*)((unsigned short*)out + (size_t)d * 128 + c) = u;
        } else {
            o0 += ((const float*)b2)[c];
            o1 += ((const float*)b2)[c + 1];
            o2 += ((const float*)b2)[c + 2];
            o3 += ((const float*)b2)[c + 3];
            *(float4*)((float*)out + (size_t)d * 128 + c) = make_float4(o0, o1, o2, o3);
        }
    }
}

// ---- diagnostic: workspace too small -> fill out with recognizable sentinel
__global__ __launch_bounds__(256) void k_sentinel(unsigned short* __restrict__ out, int total) {
    int t = blockIdx.x * 256 + threadIdx.x;
    if (t < total) out[t] = 0x4641;              // bf16(12344)
}

extern "C" void kernel_launch(void* const* d_in, const int* in_sizes, int n_in,
                              void* d_out, int out_size, void* d_ws, size_t ws_size,
                              hipStream_t stream) {
    const int n = out_size / DOUT;               // 100000

    // ---- identify inputs by unique flat element counts; positional fallback.
    const void *x = nullptr, *W1 = nullptr, *b1 = nullptr, *W2 = nullptr, *b2 = nullptr;
    const void* ei_raw = nullptr;
    int E = 0;
    const long long nx = (long long)n * DIN;
    for (int i = 0; i < n_in; ++i) {
        long long s = in_sizes[i];
        if      (s == nx && !x)                      x  = d_in[i];
        else if (s == (long long)DIN * DIN && !W1)   W1 = d_in[i];
        else if (s == (long long)DIN && !b1)         b1 = d_in[i];
        else if (s == (long long)DIN * DOUT && !W2)  W2 = d_in[i];
        else if (s == (long long)DOUT && !b2)        b2 = d_in[i];
        else if (s == 1) { /* original_size scalar */ }
        else if (!ei_raw) { ei_raw = d_in[i]; E = (int)(s / 2); }
    }
    if (!x || !W1 || !b1 || !W2 || !b2 || !ei_raw) {   // fallback: documented order
        x  = d_in[0];
        ei_raw = d_in[1];  E = in_sizes[1] / 2;
        W1 = d_in[3]; b1 = d_in[4]; W2 = d_in[5]; b2 = d_in[6];
    }

    const int nb_scan = (n + 255) / 256;         // 391

    // ---- workspace layout
    char* ws = (char*)d_ws;
    size_t off = 0;
    auto alloc = [&](size_t bytes) { void* p = ws + off; off = (off + bytes + 255) & ~255ULL; return p; };
    int*   eflag    = (int*)alloc(4);
    int*   fflag    = (int*)alloc(4);
    int*   degi     = (int*)alloc((size_t)n * 4);
    float* dinv     = (float*)alloc((size_t)n * 4);
    float* b12      = (float*)alloc(DOUT * 4);
    __hip_bfloat16* w12p = (__hip_bfloat16*)alloc(DIN * DOUT * 2);
    int*   row_ptr  = (int*)alloc(((size_t)n + 1) * 4);
    int*   cursor   = (int*)alloc((size_t)n * 4);
    int*   blocksum = (int*)alloc(512 * 4);
    int2*  csr      = (int2*)alloc((size_t)E * 8);
    float* M        = (float*)alloc((size_t)n * DOUT * 4);   // x@W12
    float* B1       = (float*)alloc((size_t)n * DOUT * 4);   // A·M

    if (ws_size < off) {   // workspace insufficient -> sentinel output, bail
        k_sentinel<<<(out_size + 255) / 256, 256, 0, stream>>>((unsigned short*)d_out, out_size);
        return;
    }

    hipMemsetAsync(degi, 0, (size_t)n * 4, stream);

    // ---- dtype detection
    k_fdetect<<<1, 256, 0, stream>>>((const unsigned short*)x, fflag);
    k_edetect<<<1, 256, 0, stream>>>((const int*)ei_raw, eflag);

    // ---- weights
    k_w12<<<(DIN * DOUT) / 256, 256, 0, stream>>>(W1, W2, fflag, w12p);
    k_b12<<<1, 128, 0, stream>>>(b1, W2, fflag, b12);

    // ---- graph preprocessing: degree -> (dinv fused in scan1) -> CSR
    k_deg<<<(E + 255) / 256, 256, 0, stream>>>(ei_raw, eflag, E, degi);
    k_scan1<<<nb_scan, 256, 0, stream>>>(degi, row_ptr, blocksum, dinv, n);
    k_scan2<<<1, 512, 0, stream>>>(blocksum, nb_scan);
    k_scan3<<<nb_scan, 256, 0, stream>>>(row_ptr, cursor, blocksum, n, E);
    k_fill<<<(E + 255) / 256, 256, 0, stream>>>(ei_raw, eflag, E, dinv, cursor, csr);

    // ---- GEMM: M = x @ W12   (16 rows per wave)
    int waves = (n + 15) / 16;
    k_gemm<<<(waves + 3) / 4, 256, 0, stream>>>(x, (const short*)w12p, fflag, M, n);

    // ---- two CSR-gather aggregations (second one fuses bias epilogue + store)
    int nb_g = (n + 3) / 4;
    k_gather<false><<<nb_g, 256, 0, stream>>>(row_ptr, csr, dinv, M, B1,
                                              nullptr, nullptr, fflag, nullptr, n);
    k_gather<true><<<nb_g, 256, 0, stream>>>(row_ptr, csr, dinv, B1, nullptr,
                                             b12, b2, fflag, d_out, n);
}

// Round 3
// 659.364 us; speedup vs baseline: 1.1337x; 1.0574x over previous
//
#include <hip/hip_runtime.h>
#include <hip/hip_bf16.h>

// GCN 2-layer fused:  out = A·A·(x @ (W1@W2)) + (A·1)⊗(b1@W2) + b2
// A = D^-1/2 (Adj + I) D^-1/2.  Aggregation is CSR gather (no fp32 atomics):
//   out[d] = dinv[d]*( sum_{s->d} dinv[s]*F[s] + dinv[d]*F[d] )
// Runtime-detects float dtype (f32 vs bf16) and edge dtype (int32 vs int64).
//
// R3 = R2 resubmit (container infra flake, no data).  Theory: VMEM *instruction-
// issue* bound (~64 cyc per wave64 VMEM instr, per CU).
//  - k_gemm: 64 rows/wave (B-instr amortized 4x vs R1); operand-swapped MFMA
//    (mfma(B,A) -> transposed fragment) so stores are float4 (32/wave, was 128 dwords).
//  - k_w12: thread owns (d, 4 cols), float4 loads both operands (was 1M scalar-loads).
//  - k_gather: 16 nodes/wave; row_ptr batch-prefetch (1 instr/chunk); csr batch-prefetch
//    (1 instr/64 edges) + shfl broadcast; dinv recomputed from row_ptr (0 loads).

typedef __attribute__((ext_vector_type(8))) short short8;   // 8 bf16 (4 VGPRs)
typedef __attribute__((ext_vector_type(4))) float f32x4;

#define DIN 512
#define DOUT 128

__device__ inline short f2bs(float f) {
    __hip_bfloat16 h = __float2bfloat16(f);
    return __builtin_bit_cast(short, h);
}
__device__ inline float b2f(const void* p, long long idx) {
    return __bfloat162float(((const __hip_bfloat16*)p)[idx]);
}
__device__ inline float bsu(unsigned short v) {
    return __bfloat162float(__builtin_bit_cast(__hip_bfloat16, v));
}
__device__ inline int edge_at(const void* ei, int eflag, long long idx) {
    return eflag ? ((const int*)ei)[idx] : (int)((const long long*)ei)[idx];
}

// ---- float dtype detect on x: bf16 data -> ~100% of uint16s have N(0,1)-plausible
//      exponents; f32 data -> low-mantissa halves are uniform -> ~56%.  fflag=1 => bf16.
__global__ void k_fdetect(const unsigned short* __restrict__ xr, int* __restrict__ fflag) {
    __shared__ int cnt;
    if (threadIdx.x == 0) cnt = 0;
    __syncthreads();
    int local = 0;
    for (int i = threadIdx.x; i < 8192; i += 256) {
        unsigned e = (xr[i] >> 7) & 0xFF;
        if (e == 0 || (e >= 0x70 && e <= 0x8E)) local++;
    }
    atomicAdd(&cnt, local);
    __syncthreads();
    if (threadIdx.x == 0) *fflag = (cnt >= 7373) ? 1 : 0;   // >=90% plausible => bf16
}

// ---- edge dtype detect: odd int32 words of int64 node ids are all zero.  eflag=1 => int32.
__global__ void k_edetect(const int* __restrict__ ei_raw, int* __restrict__ eflag) {
    __shared__ int any;
    if (threadIdx.x == 0) any = 0;
    __syncthreads();
    for (int i = threadIdx.x; i < 4096; i += 256)
        if (ei_raw[2 * i + 1] != 0) any = 1;   // benign race
    __syncthreads();
    if (threadIdx.x == 0) *eflag = any;
}

// ---- W12 = W1@W2 packed for coalesced MFMA fragment loads.
//      Thread owns (d, j0..j0+3): vectorized loads -> ~5 VMEM instrs per 4 k-steps.
//      w12p[((ks*8+nc)*64 + quad*16 + m16)*8 + jj] = W12[k=ks*32+quad*8+jj][col=nc*16+m16]
__global__ __launch_bounds__(256) void k_w12(const void* __restrict__ W1,
                                             const void* __restrict__ W2,
                                             const int* __restrict__ fflag,
                                             __hip_bfloat16* __restrict__ w12p) {
    int t = blockIdx.x * 256 + threadIdx.x;      // [0, 512*32)
    int d = t >> 5, j0 = (t & 31) * 4;
    float4 acc = make_float4(0.f, 0.f, 0.f, 0.f);
    if (*fflag) {
        const short* w1s = (const short*)W1;
        const unsigned short* w2u = (const unsigned short*)W2;
        for (int c8 = 0; c8 < 512; c8 += 8) {
            short8 av = *(const short8*)(w1s + (size_t)d * 512 + c8);
#pragma unroll
            for (int k = 0; k < 8; ++k) {
                float a = bsu((unsigned short)av[k]);
                ushort4 u = *(const ushort4*)(w2u + (size_t)(c8 + k) * 128 + j0);
                acc.x += a * bsu(u.x); acc.y += a * bsu(u.y);
                acc.z += a * bsu(u.z); acc.w += a * bsu(u.w);
            }
        }
    } else {
        const float* w1 = (const float*)W1;
        const float* w2 = (const float*)W2;
        for (int c4 = 0; c4 < 512; c4 += 4) {
            float4 a  = *(const float4*)(w1 + (size_t)d * 512 + c4);
            float4 r0 = *(const float4*)(w2 + (size_t)(c4 + 0) * 128 + j0);
            float4 r1 = *(const float4*)(w2 + (size_t)(c4 + 1) * 128 + j0);
            float4 r2 = *(const float4*)(w2 + (size_t)(c4 + 2) * 128 + j0);
            float4 r3 = *(const float4*)(w2 + (size_t)(c4 + 3) * 128 + j0);
            acc.x += a.x * r0.x + a.y * r1.x + a.z * r2.x + a.w * r3.x;
            acc.y += a.x * r0.y + a.y * r1.y + a.z * r2.y + a.w * r3.y;
            acc.z += a.x * r0.z + a.y * r1.z + a.z * r2.z + a.w * r3.z;
            acc.w += a.x * r0.w + a.y * r1.w + a.z * r2.w + a.w * r3.w;
        }
    }
    int ks = d >> 5, r = d & 31;
    int quad = r >> 3, jj = r & 7;
    float av[4] = {acc.x, acc.y, acc.z, acc.w};
#pragma unroll
    for (int q = 0; q < 4; ++q) {
        int j = j0 + q, nc = j >> 4, m16 = j & 15;
        w12p[(((size_t)(ks * 8 + nc) * 64) + quad * 16 + m16) * 8 + jj] = __float2bfloat16(av[q]);
    }
}

// ---- b12[j] = sum_c b1[c] * W2[c,j]  (fp32)
__global__ void k_b12(const void* __restrict__ b1, const void* __restrict__ W2,
                      const int* __restrict__ fflag, float* __restrict__ b12) {
    int j = threadIdx.x;                         // 128 threads
    float acc = 0.f;
    if (*fflag) {
        for (int c = 0; c < 512; ++c)
            acc += b2f(b1, c) * b2f(W2, c * 128 + j);
    } else {
        const float* bb = (const float*)b1;
        const float* w2 = (const float*)W2;
        for (int c = 0; c < 512; ++c)
            acc += bb[c] * w2[c * 128 + j];
    }
    b12[j] = acc;
}

// ---- in-degree over dst (real edges; self-loop added analytically)
__global__ __launch_bounds__(256) void k_deg(const void* __restrict__ ei,
                                             const int* __restrict__ eflag, int E,
                                             int* __restrict__ degi) {
    int e = blockIdx.x * 256 + threadIdx.x;
    if (e >= E) return;
    atomicAdd(&degi[edge_at(ei, *eflag, (long long)E + e)], 1);
}

// ---- exclusive scan over degi -> row_ptr (3-kernel two-level scan); dinv fused here
__global__ __launch_bounds__(256) void k_scan1(const int* __restrict__ degi,
                                               int* __restrict__ row_ptr,
                                               int* __restrict__ blocksum,
                                               float* __restrict__ dinv, int n) {
    __shared__ int sh[256];
    int t = threadIdx.x, g = blockIdx.x * 256 + t;
    int val = (g < n) ? degi[g] : 0;
    if (g < n) dinv[g] = rsqrtf((float)(val + 1));    // +1: self-loop
    sh[t] = val;
    __syncthreads();
    for (int o = 1; o < 256; o <<= 1) {
        int v = (t >= o) ? sh[t - o] : 0;
        __syncthreads();
        if (t >= o) sh[t] += v;
        __syncthreads();
    }
    if (g < n) row_ptr[g] = sh[t] - val;         // exclusive within block
    if (t == 255) blocksum[blockIdx.x] = sh[255];
}

__global__ void k_scan2(int* __restrict__ blocksum, int nb) {
    __shared__ int sh[512];
    int t = threadIdx.x;
    int val = (t < nb) ? blocksum[t] : 0;
    sh[t] = val;
    __syncthreads();
    for (int o = 1; o < 512; o <<= 1) {
        int v = (t >= o) ? sh[t - o] : 0;
        __syncthreads();
        if (t >= o) sh[t] += v;
        __syncthreads();
    }
    if (t < nb) blocksum[t] = sh[t] - val;       // exclusive
}

__global__ __launch_bounds__(256) void k_scan3(int* __restrict__ row_ptr,
                                               int* __restrict__ cursor,
                                               const int* __restrict__ blocksum,
                                               int n, int E) {
    int g = blockIdx.x * 256 + threadIdx.x;
    if (g == 0) row_ptr[n] = E;
    if (g >= n) return;
    int v = row_ptr[g] + blocksum[blockIdx.x];
    row_ptr[g] = v;
    cursor[g] = v;
}

// ---- CSR fill: csr[pos] = (src, dinv[src]) bucketed by dst (order arbitrary)
__global__ __launch_bounds__(256) void k_fill(const void* __restrict__ ei,
                                              const int* __restrict__ eflag, int E,
                                              const float* __restrict__ dinv,
                                              int* __restrict__ cursor,
                                              int2* __restrict__ csr) {
    int e = blockIdx.x * 256 + threadIdx.x;
    if (e >= E) return;
    int f = *eflag;
    int s = edge_at(ei, f, e);
    int d = edge_at(ei, f, (long long)E + e);
    int pos = atomicAdd(&cursor[d], 1);
    csr[pos] = make_int2(s, __float_as_int(dinv[s]));
}

// ---- M = x @ W12   (bf16 MFMA, fp32 out).  One wave: 64 rows x 128 cols.
//      Operand-swapped MFMA: acc = mfma(Bfrag, Afrag) -> lane (quad,m16) reg r holds
//      M[row0+g*16+m16][nc*16+quad*4+r]  => direct float4 stores (32 instrs/wave).
__global__ __launch_bounds__(64, 1) void k_gemm(const void* __restrict__ xv,
                                                const short* __restrict__ w12p,
                                                const int* __restrict__ fflag,
                                                float* __restrict__ M, int n) {
    int lane = threadIdx.x;                      // block = 1 wave
    int row0 = blockIdx.x * 64;
    if (row0 >= n) return;
    int quad = lane >> 4, m16 = lane & 15;
    const short8* Bp = (const short8*)w12p;      // index: (ks*8+nc)*64 + lane

    f32x4 acc[4][8];
#pragma unroll
    for (int g = 0; g < 4; ++g)
#pragma unroll
        for (int nc = 0; nc < 8; ++nc) acc[g][nc] = (f32x4){0.f, 0.f, 0.f, 0.f};

    int ra[4];
#pragma unroll
    for (int g = 0; g < 4; ++g) {
        int r = row0 + g * 16 + m16;
        ra[g] = (r < n) ? r : (n - 1);           // tail-safe (reads only)
    }

    if (*fflag) {            // ---- bf16 input path
        const short* xs = (const short*)xv;
        for (int ks = 0; ks < 16; ++ks) {
            int k0 = ks * 32 + quad * 8;
            short8 B[8];
#pragma unroll
            for (int nc = 0; nc < 8; ++nc) B[nc] = Bp[(ks * 8 + nc) * 64 + lane];
#pragma unroll
            for (int g = 0; g < 4; ++g) {
                short8 A = *(const short8*)(xs + (size_t)ra[g] * 512 + k0);
#pragma unroll
                for (int nc = 0; nc < 8; ++nc)
                    acc[g][nc] = __builtin_amdgcn_mfma_f32_16x16x32_bf16(B[nc], A, acc[g][nc], 0, 0, 0);
            }
        }
    } else {                 // ---- f32 input path: load f32, cvt to bf16 fragments
        const float* xf = (const float*)xv;
        for (int ks = 0; ks < 16; ++ks) {
            int k0 = ks * 32 + quad * 8;
            short8 B[8];
#pragma unroll
            for (int nc = 0; nc < 8; ++nc) B[nc] = Bp[(ks * 8 + nc) * 64 + lane];
#pragma unroll
            for (int g = 0; g < 4; ++g) {
                float4 u0 = *(const float4*)(xf + (size_t)ra[g] * 512 + k0);
                float4 u1 = *(const float4*)(xf + (size_t)ra[g] * 512 + k0 + 4);
                short8 A;
                A[0] = f2bs(u0.x); A[1] = f2bs(u0.y); A[2] = f2bs(u0.z); A[3] = f2bs(u0.w);
                A[4] = f2bs(u1.x); A[5] = f2bs(u1.y); A[6] = f2bs(u1.z); A[7] = f2bs(u1.w);
#pragma unroll
                for (int nc = 0; nc < 8; ++nc)
                    acc[g][nc] = __builtin_amdgcn_mfma_f32_16x16x32_bf16(B[nc], A, acc[g][nc], 0, 0, 0);
            }
        }
    }
#pragma unroll
    for (int g = 0; g < 4; ++g) {
        int rowr = row0 + g * 16 + m16;
        if (rowr < n) {
#pragma unroll
            for (int nc = 0; nc < 8; ++nc)
                *(f32x4*)(M + (size_t)rowr * 128 + nc * 16 + quad * 4) = acc[g][nc];
        }
    }
}

#define GC 16   // nodes per wave in gather

// ---- CSR gather: one wave per GC-node chunk; half-wave (32 lanes x float4) per edge.
//      csr records batch-prefetched 64/instr + shfl broadcast; row_ptr chunk prefetched
//      in one instr; dinv recomputed from row_ptr diff (no loads).
//      FINAL=false: dstf[d] = dinv[d]*(sum + dinv[d]*src[d])
//      FINAL=true : fused epilogue  out = acc + dinv[d]*(wsum+dinv[d])*b12 + b2
template <bool FINAL>
__global__ __launch_bounds__(256) void k_gather(const int* __restrict__ row_ptr,
                                                const int2* __restrict__ csr,
                                                const float* __restrict__ src_feat,
                                                float* __restrict__ dstf,
                                                const float* __restrict__ b12,
                                                const void* __restrict__ b2,
                                                const int* __restrict__ fflag,
                                                void* __restrict__ out, int n, int E) {
    int wave = (blockIdx.x * 256 + threadIdx.x) >> 6;
    int lane = threadIdx.x & 63;
    int half = lane >> 5, sl = lane & 31;
    int c = sl * 4;
    int d0 = wave * GC;
    if (d0 >= n) return;

    // one-instr prefetch of row_ptr[d0 .. d0+GC]
    int rpq = min(d0 + lane, n);
    int rpv = row_ptr[rpq];

    // hoisted epilogue operands (FINAL only)
    float4 bv = make_float4(0.f, 0.f, 0.f, 0.f);
    float4 b2v = make_float4(0.f, 0.f, 0.f, 0.f);
    int ff = 0;
    if (FINAL) {
        ff = *fflag;
        bv = *(const float4*)(b12 + c);
        if (ff) {
            ushort4 u = *(const ushort4*)((const unsigned short*)b2 + c);
            b2v = make_float4(bsu(u.x), bsu(u.y), bsu(u.z), bsu(u.w));
        } else {
            b2v = *(const float4*)((const float*)b2 + c);
        }
    }

    for (int i = 0; i < GC; ++i) {
        int d = d0 + i;
        if (d >= n) break;
        int beg = __shfl(rpv, i);
        int end = __shfl(rpv, i + 1);
        int deg = end - beg;
        float di = rsqrtf((float)(deg + 1));

        float ax = 0.f, ay = 0.f, az = 0.f, aw = 0.f, wsum = 0.f;
        if (half == 0) {
            float4 s = *(const float4*)(src_feat + (size_t)d * 128 + c);
            ax = di * s.x; ay = di * s.y; az = di * s.z; aw = di * s.w;
        }
        for (int ch = 0; ch < deg; ch += 64) {
            int idx = beg + ch + lane;
            if (idx >= E) idx = E - 1;            // safe over-read, never consumed
            if (idx < 0) idx = 0;
            int2 rec = csr[idx];                  // 64 edge records in one instr
            int lim = deg - ch; if (lim > 64) lim = 64;
            for (int t = half; t < lim; t += 2) {
                int srcn = __shfl(rec.x, t);
                float w = __int_as_float(__shfl(rec.y, t));
                float4 v = *(const float4*)(src_feat + (size_t)srcn * 128 + c);
                ax += w * v.x; ay += w * v.y; az += w * v.z; aw += w * v.w;
                wsum += w;
            }
        }
        // combine the two halves (lane i <-> lane i+32)
        ax += __shfl_xor(ax, 32);
        ay += __shfl_xor(ay, 32);
        az += __shfl_xor(az, 32);
        aw += __shfl_xor(aw, 32);
        wsum += __shfl_xor(wsum, 32);
        if (half == 0) {
            ax *= di; ay *= di; az *= di; aw *= di;
            if (!FINAL) {
                *(float4*)(dstf + (size_t)d * 128 + c) = make_float4(ax, ay, az, aw);
            } else {
                float coef = di * (wsum + di);
                float o0 = ax + coef * bv.x + b2v.x;
                float o1 = ay + coef * bv.y + b2v.y;
                float o2 = az + coef * bv.z + b2v.z;
                float o3 = aw + coef * bv.w + b2v.w;
                if (ff) {
                    ushort4 u = make_ushort4((unsigned short)f2bs(o0), (unsigned short)f2bs(o1),
                                             (unsigned short)f2bs(o2), (unsigned short)f2bs(o3));
                    *(ushort4*)((unsigned short*)out + (size_t)d * 128 + c) = u;
                } else {
                    *(float4*)((float*)out + (size_t)d * 128 + c) = make_float4(o0, o1, o2, o3);
                }
            }
        }
    }
}

// ---- diagnostic: workspace too small -> fill out with recognizable sentinel
__global__ __launch_bounds__(256) void k_sentinel(unsigned short* __restrict__ out, int total) {
    int t = blockIdx.x * 256 + threadIdx.x;
    if (t < total) out[t] = 0x4641;              // bf16(12344)
}

extern "C" void kernel_launch(void* const* d_in, const int* in_sizes, int n_in,
                              void* d_out, int out_size, void* d_ws, size_t ws_size,
                              hipStream_t stream) {
    const int n = out_size / DOUT;               // 100000

    // ---- identify inputs by unique flat element counts; positional fallback.
    const void *x = nullptr, *W1 = nullptr, *b1 = nullptr, *W2 = nullptr, *b2 = nullptr;
    const void* ei_raw = nullptr;
    int E = 0;
    const long long nx = (long long)n * DIN;
    for (int i = 0; i < n_in; ++i) {
        long long s = in_sizes[i];
        if      (s == nx && !x)                      x  = d_in[i];
        else if (s == (long long)DIN * DIN && !W1)   W1 = d_in[i];
        else if (s == (long long)DIN && !b1)         b1 = d_in[i];
        else if (s == (long long)DIN * DOUT && !W2)  W2 = d_in[i];
        else if (s == (long long)DOUT && !b2)        b2 = d_in[i];
        else if (s == 1) { /* original_size scalar */ }
        else if (!ei_raw) { ei_raw = d_in[i]; E = (int)(s / 2); }
    }
    if (!x || !W1 || !b1 || !W2 || !b2 || !ei_raw) {   // fallback: documented order
        x  = d_in[0];
        ei_raw = d_in[1];  E = in_sizes[1] / 2;
        W1 = d_in[3]; b1 = d_in[4]; W2 = d_in[5]; b2 = d_in[6];
    }
    if (E < 1) E = 1;

    const int nb_scan = (n + 255) / 256;         // 391

    // ---- workspace layout
    char* ws = (char*)d_ws;
    size_t off = 0;
    auto alloc = [&](size_t bytes) { void* p = ws + off; off = (off + bytes + 255) & ~255ULL; return p; };
    int*   eflag    = (int*)alloc(4);
    int*   fflag    = (int*)alloc(4);
    int*   degi     = (int*)alloc((size_t)n * 4);
    float* dinv     = (float*)alloc((size_t)n * 4);
    float* b12      = (float*)alloc(DOUT * 4);
    __hip_bfloat16* w12p = (__hip_bfloat16*)alloc(DIN * DOUT * 2);
    int*   row_ptr  = (int*)alloc(((size_t)n + 1) * 4);
    int*   cursor   = (int*)alloc((size_t)n * 4);
    int*   blocksum = (int*)alloc(512 * 4);
    int2*  csr      = (int2*)alloc((size_t)E * 8);
    float* M        = (float*)alloc((size_t)n * DOUT * 4);   // x@W12
    float* B1       = (float*)alloc((size_t)n * DOUT * 4);   // A·M

    if (ws_size < off) {   // workspace insufficient -> sentinel output, bail
        k_sentinel<<<(out_size + 255) / 256, 256, 0, stream>>>((unsigned short*)d_out, out_size);
        return;
    }

    hipMemsetAsync(degi, 0, (size_t)n * 4, stream);

    // ---- dtype detection
    k_fdetect<<<1, 256, 0, stream>>>((const unsigned short*)x, fflag);
    k_edetect<<<1, 256, 0, stream>>>((const int*)ei_raw, eflag);

    // ---- weights
    k_w12<<<(DIN * 32) / 256, 256, 0, stream>>>(W1, W2, fflag, w12p);
    k_b12<<<1, 128, 0, stream>>>(b1, W2, fflag, b12);

    // ---- graph preprocessing: degree -> (dinv fused in scan1) -> CSR
    k_deg<<<(E + 255) / 256, 256, 0, stream>>>(ei_raw, eflag, E, degi);
    k_scan1<<<nb_scan, 256, 0, stream>>>(degi, row_ptr, blocksum, dinv, n);
    k_scan2<<<1, 512, 0, stream>>>(blocksum, nb_scan);
    k_scan3<<<nb_scan, 256, 0, stream>>>(row_ptr, cursor, blocksum, n, E);
    k_fill<<<(E + 255) / 256, 256, 0, stream>>>(ei_raw, eflag, E, dinv, cursor, csr);

    // ---- GEMM: M = x @ W12   (64 rows per wave, 1-wave blocks for load balance)
    k_gemm<<<(n + 63) / 64, 64, 0, stream>>>(x, (const short*)w12p, fflag, M, n);

    // ---- two CSR-gather aggregations (second one fuses bias epilogue + store)
    int gwaves = (n + GC - 1) / GC;
    int gb = (gwaves + 3) / 4;
    k_gather<false><<<gb, 256, 0, stream>>>(row_ptr, csr, M, B1,
                                            nullptr, nullptr, fflag, nullptr, n, E);
    k_gather<true><<<gb, 256, 0, stream>>>(row_ptr, csr, B1, nullptr,
                                           b12, b2, fflag, d_out, n, E);
}

// Round 5
// 628.115 us; speedup vs baseline: 1.1901x; 1.0498x over previous
//
#include <hip/hip_runtime.h>
#include <hip/hip_bf16.h>

// GCN 2-layer fused:  out = A·A·(x @ (W1@W2)) + (A·1)⊗(b1@W2) + b2
// A = D^-1/2 (Adj + I) D^-1/2.  Aggregation is CSR gather (no fp32 atomics):
//   out[d] = dinv[d]*( sum_{s->d} dinv[s]*F[s] + dinv[d]*F[d] )
// Runtime-detects float dtype (f32 vs bf16) and edge dtype (int32 vs int64).
//
// R5: R3's verified fp32 datapath (fp16 intermediates FAILED accuracy in R4 --
// harness verification data is not unit-scale; intermediates must stay fp32)
// + R4's structural fusion only (9 dispatches):
//  - k_pre fuses degi-zero + both dtype detects.
//  - b12 fused into k_w12 (block 64).
//  - dinv array dropped: k_fill recomputes from degi, gather from row_ptr diff.
//  - scan2 folded into scan3 (each block redundantly scans blocksums in LDS).

typedef __attribute__((ext_vector_type(8))) short short8;    // 8 bf16 (4 VGPRs)
typedef __attribute__((ext_vector_type(4))) float f32x4;

#define DIN 512
#define DOUT 128
#define GC 16   // nodes per wave in gather

__device__ inline short f2bs(float f) {
    __hip_bfloat16 h = __float2bfloat16(f);
    return __builtin_bit_cast(short, h);
}
__device__ inline float b2f(const void* p, long long idx) {
    return __bfloat162float(((const __hip_bfloat16*)p)[idx]);
}
__device__ inline float bsu(unsigned short v) {
    return __bfloat162float(__builtin_bit_cast(__hip_bfloat16, v));
}
__device__ inline int edge_at(const void* ei, int eflag, long long idx) {
    return eflag ? ((const int*)ei)[idx] : (int)((const long long*)ei)[idx];
}

// ---- k_pre: blocks [0,nzb) zero degi; block nzb = float-dtype detect;
//      block nzb+1 = edge-dtype detect.
//      fdetect: bf16 data -> ~100% of uint16s have N(0,1)-plausible exponents;
//      f32 data -> low-mantissa halves uniform -> ~56%.  fflag=1 => bf16.
//      edetect: odd int32 words of int64 ids all zero => int32 (eflag=1).
__global__ __launch_bounds__(256) void k_pre(int* __restrict__ degi, int n, int nzb,
                                             const unsigned short* __restrict__ xr,
                                             int* __restrict__ fflag,
                                             const int* __restrict__ ei_raw,
                                             int* __restrict__ eflag) {
    __shared__ int acc;
    int b = blockIdx.x;
    if (b < nzb) {
        int g = b * 256 + threadIdx.x;
        if (g < n) degi[g] = 0;
        return;
    }
    if (threadIdx.x == 0) acc = 0;
    __syncthreads();
    if (b == nzb) {
        int local = 0;
        for (int i = threadIdx.x; i < 8192; i += 256) {
            unsigned e = (xr[i] >> 7) & 0xFF;
            if (e == 0 || (e >= 0x70 && e <= 0x8E)) local++;
        }
        atomicAdd(&acc, local);
        __syncthreads();
        if (threadIdx.x == 0) *fflag = (acc >= 7373) ? 1 : 0;   // >=90% => bf16
    } else {
        for (int i = threadIdx.x; i < 4096; i += 256)
            if (ei_raw[2 * i + 1] != 0) acc = 1;   // benign race
        __syncthreads();
        if (threadIdx.x == 0) *eflag = acc;
    }
}

// ---- W12 = W1@W2 packed for coalesced MFMA fragment loads (blocks 0..63);
//      block 64: b12[j] = sum_c b1[c]*W2[c,j].
//      w12p[((ks*8+nc)*64 + quad*16 + m16)*8 + jj] = W12[k=ks*32+quad*8+jj][col=nc*16+m16]
__global__ __launch_bounds__(256) void k_w12(const void* __restrict__ W1,
                                             const void* __restrict__ W2,
                                             const void* __restrict__ b1,
                                             const int* __restrict__ fflag,
                                             __hip_bfloat16* __restrict__ w12p,
                                             float* __restrict__ b12) {
    if (blockIdx.x == 64) {                      // ---- b12
        int j = threadIdx.x;
        if (j >= 128) return;
        float acc = 0.f;
        if (*fflag) {
            for (int c = 0; c < 512; ++c)
                acc += b2f(b1, c) * b2f(W2, c * 128 + j);
        } else {
            const float* bb = (const float*)b1;
            const float* w2 = (const float*)W2;
            for (int c = 0; c < 512; ++c)
                acc += bb[c] * w2[c * 128 + j];
        }
        b12[j] = acc;
        return;
    }
    int t = blockIdx.x * 256 + threadIdx.x;      // [0, 512*32)
    int d = t >> 5, j0 = (t & 31) * 4;
    float4 acc = make_float4(0.f, 0.f, 0.f, 0.f);
    if (*fflag) {
        const short* w1s = (const short*)W1;
        const unsigned short* w2u = (const unsigned short*)W2;
        for (int c8 = 0; c8 < 512; c8 += 8) {
            short8 av = *(const short8*)(w1s + (size_t)d * 512 + c8);
#pragma unroll
            for (int k = 0; k < 8; ++k) {
                float a = bsu((unsigned short)av[k]);
                ushort4 u = *(const ushort4*)(w2u + (size_t)(c8 + k) * 128 + j0);
                acc.x += a * bsu(u.x); acc.y += a * bsu(u.y);
                acc.z += a * bsu(u.z); acc.w += a * bsu(u.w);
            }
        }
    } else {
        const float* w1 = (const float*)W1;
        const float* w2 = (const float*)W2;
        for (int c4 = 0; c4 < 512; c4 += 4) {
            float4 a  = *(const float4*)(w1 + (size_t)d * 512 + c4);
            float4 r0 = *(const float4*)(w2 + (size_t)(c4 + 0) * 128 + j0);
            float4 r1 = *(const float4*)(w2 + (size_t)(c4 + 1) * 128 + j0);
            float4 r2 = *(const float4*)(w2 + (size_t)(c4 + 2) * 128 + j0);
            float4 r3 = *(const float4*)(w2 + (size_t)(c4 + 3) * 128 + j0);
            acc.x += a.x * r0.x + a.y * r1.x + a.z * r2.x + a.w * r3.x;
            acc.y += a.x * r0.y + a.y * r1.y + a.z * r2.y + a.w * r3.y;
            acc.z += a.x * r0.z + a.y * r1.z + a.z * r2.z + a.w * r3.z;
            acc.w += a.x * r0.w + a.y * r1.w + a.z * r2.w + a.w * r3.w;
        }
    }
    int ks = d >> 5, r = d & 31;
    int quad = r >> 3, jj = r & 7;
    float av[4] = {acc.x, acc.y, acc.z, acc.w};
#pragma unroll
    for (int q = 0; q < 4; ++q) {
        int j = j0 + q, nc = j >> 4, m16 = j & 15;
        w12p[(((size_t)(ks * 8 + nc) * 64) + quad * 16 + m16) * 8 + jj] = __float2bfloat16(av[q]);
    }
}

// ---- in-degree over dst (real edges; self-loop added analytically)
__global__ __launch_bounds__(256) void k_deg(const void* __restrict__ ei,
                                             const int* __restrict__ eflag, int E,
                                             int* __restrict__ degi) {
    int e = blockIdx.x * 256 + threadIdx.x;
    if (e >= E) return;
    atomicAdd(&degi[edge_at(ei, *eflag, (long long)E + e)], 1);
}

// ---- exclusive scan over degi: per-block exclusive + blocksum
__global__ __launch_bounds__(256) void k_scan1(const int* __restrict__ degi,
                                               int* __restrict__ row_ptr,
                                               int* __restrict__ blocksum, int n) {
    __shared__ int sh[256];
    int t = threadIdx.x, g = blockIdx.x * 256 + t;
    int val = (g < n) ? degi[g] : 0;
    sh[t] = val;
    __syncthreads();
    for (int o = 1; o < 256; o <<= 1) {
        int v = (t >= o) ? sh[t - o] : 0;
        __syncthreads();
        if (t >= o) sh[t] += v;
        __syncthreads();
    }
    if (g < n) row_ptr[g] = sh[t] - val;         // exclusive within block
    if (t == 255) blocksum[blockIdx.x] = sh[255];
}

// ---- scan3 with folded block-sum scan: each block redundantly scans blocksum
//      (nbs <= 512) in LDS, then offsets its 256-node slice.
__global__ __launch_bounds__(512) void k_scan3(int* __restrict__ row_ptr,
                                               int* __restrict__ cursor,
                                               const int* __restrict__ blocksum,
                                               int nbs, int n, int E) {
    __shared__ int sh[512];
    int t = threadIdx.x;
    int val = (t < nbs) ? blocksum[t] : 0;
    sh[t] = val;
    __syncthreads();
    for (int o = 1; o < 512; o <<= 1) {
        int v = (t >= o) ? sh[t - o] : 0;
        __syncthreads();
        if (t >= o) sh[t] += v;
        __syncthreads();
    }
    int excl = sh[blockIdx.x] - blocksum[blockIdx.x];   // exclusive prefix @ this block
    if (t >= 256) return;
    int g = blockIdx.x * 256 + t;
    if (g == 0) row_ptr[n] = E;
    if (g >= n) return;
    int v = row_ptr[g] + excl;
    row_ptr[g] = v;
    cursor[g] = v;
}

// legacy pair for nbs > 512 (not expected at n=100000; safety fallback)
__global__ void k_scan2(int* __restrict__ blocksum, int nb) {
    __shared__ int sh[512];
    int t = threadIdx.x;
    int val = (t < nb) ? blocksum[t] : 0;
    sh[t] = val;
    __syncthreads();
    for (int o = 1; o < 512; o <<= 1) {
        int v = (t >= o) ? sh[t - o] : 0;
        __syncthreads();
        if (t >= o) sh[t] += v;
        __syncthreads();
    }
    if (t < nb) blocksum[t] = sh[t] - val;
}
__global__ __launch_bounds__(256) void k_scan3b(int* __restrict__ row_ptr,
                                                int* __restrict__ cursor,
                                                const int* __restrict__ blocksum,
                                                int n, int E) {
    int g = blockIdx.x * 256 + threadIdx.x;
    if (g == 0) row_ptr[n] = E;
    if (g >= n) return;
    int v = row_ptr[g] + blocksum[blockIdx.x];
    row_ptr[g] = v;
    cursor[g] = v;
}

// ---- CSR fill: csr[pos] = (src, dinv[src]) bucketed by dst (order arbitrary);
//      dinv[src] recomputed from degi (no dinv array).
__global__ __launch_bounds__(256) void k_fill(const void* __restrict__ ei,
                                              const int* __restrict__ eflag, int E,
                                              const int* __restrict__ degi,
                                              int* __restrict__ cursor,
                                              int2* __restrict__ csr) {
    int e = blockIdx.x * 256 + threadIdx.x;
    if (e >= E) return;
    int f = *eflag;
    int s = edge_at(ei, f, e);
    int d = edge_at(ei, f, (long long)E + e);
    float ds = rsqrtf((float)(degi[s] + 1));
    int pos = atomicAdd(&cursor[d], 1);
    csr[pos] = make_int2(s, __float_as_int(ds));
}

// ---- M = x @ W12   (bf16 MFMA, fp32 out).  One wave: 64 rows x 128 cols.
//      Operand-swapped MFMA: acc = mfma(Bfrag, Afrag) -> lane (quad,m16) reg r holds
//      M[row0+g*16+m16][nc*16+quad*4+r]  => direct float4 stores (32 instrs/wave).
__global__ __launch_bounds__(64, 1) void k_gemm(const void* __restrict__ xv,
                                                const short* __restrict__ w12p,
                                                const int* __restrict__ fflag,
                                                float* __restrict__ M, int n) {
    int lane = threadIdx.x;                      // block = 1 wave
    int row0 = blockIdx.x * 64;
    if (row0 >= n) return;
    int quad = lane >> 4, m16 = lane & 15;
    const short8* Bp = (const short8*)w12p;      // index: (ks*8+nc)*64 + lane

    f32x4 acc[4][8];
#pragma unroll
    for (int g = 0; g < 4; ++g)
#pragma unroll
        for (int nc = 0; nc < 8; ++nc) acc[g][nc] = (f32x4){0.f, 0.f, 0.f, 0.f};

    int ra[4];
#pragma unroll
    for (int g = 0; g < 4; ++g) {
        int r = row0 + g * 16 + m16;
        ra[g] = (r < n) ? r : (n - 1);           // tail-safe (reads only)
    }

    if (*fflag) {            // ---- bf16 input path
        const short* xs = (const short*)xv;
        for (int ks = 0; ks < 16; ++ks) {
            int k0 = ks * 32 + quad * 8;
            short8 B[8];
#pragma unroll
            for (int nc = 0; nc < 8; ++nc) B[nc] = Bp[(ks * 8 + nc) * 64 + lane];
#pragma unroll
            for (int g = 0; g < 4; ++g) {
                short8 A = *(const short8*)(xs + (size_t)ra[g] * 512 + k0);
#pragma unroll
                for (int nc = 0; nc < 8; ++nc)
                    acc[g][nc] = __builtin_amdgcn_mfma_f32_16x16x32_bf16(B[nc], A, acc[g][nc], 0, 0, 0);
            }
        }
    } else {                 // ---- f32 input path: load f32, cvt to bf16 fragments
        const float* xf = (const float*)xv;
        for (int ks = 0; ks < 16; ++ks) {
            int k0 = ks * 32 + quad * 8;
            short8 B[8];
#pragma unroll
            for (int nc = 0; nc < 8; ++nc) B[nc] = Bp[(ks * 8 + nc) * 64 + lane];
#pragma unroll
            for (int g = 0; g < 4; ++g) {
                float4 u0 = *(const float4*)(xf + (size_t)ra[g] * 512 + k0);
                float4 u1 = *(const float4*)(xf + (size_t)ra[g] * 512 + k0 + 4);
                short8 A;
                A[0] = f2bs(u0.x); A[1] = f2bs(u0.y); A[2] = f2bs(u0.z); A[3] = f2bs(u0.w);
                A[4] = f2bs(u1.x); A[5] = f2bs(u1.y); A[6] = f2bs(u1.z); A[7] = f2bs(u1.w);
#pragma unroll
                for (int nc = 0; nc < 8; ++nc)
                    acc[g][nc] = __builtin_amdgcn_mfma_f32_16x16x32_bf16(B[nc], A, acc[g][nc], 0, 0, 0);
            }
        }
    }
#pragma unroll
    for (int g = 0; g < 4; ++g) {
        int rowr = row0 + g * 16 + m16;
        if (rowr < n) {
#pragma unroll
            for (int nc = 0; nc < 8; ++nc)
                *(f32x4*)(M + (size_t)rowr * 128 + nc * 16 + quad * 4) = acc[g][nc];
        }
    }
}

// ---- CSR gather (fp32): one wave per GC-node chunk; half-wave (32 lanes x
//      float4 = 512 B row) per edge -> 2 edges per VMEM instr.  csr batch-
//      prefetched 64 records/instr + shfl broadcast; row_ptr chunk prefetched
//      in one instr; dinv recomputed from row_ptr diff (no loads).
//      FINAL=false: dstf[d] = dinv[d]*(sum + dinv[d]*src[d])
//      FINAL=true : out = acc + dinv[d]*(wsum+dinv[d])*b12 + b2
template <bool FINAL>
__global__ __launch_bounds__(256) void k_gather(const int* __restrict__ row_ptr,
                                                const int2* __restrict__ csr,
                                                const float* __restrict__ src_feat,
                                                float* __restrict__ dstf,
                                                const float* __restrict__ b12,
                                                const void* __restrict__ b2,
                                                const int* __restrict__ fflag,
                                                void* __restrict__ out, int n, int E) {
    int wave = (blockIdx.x * 256 + threadIdx.x) >> 6;
    int lane = threadIdx.x & 63;
    int half = lane >> 5, sl = lane & 31;
    int c = sl * 4;
    int d0 = wave * GC;
    if (d0 >= n) return;

    // one-instr prefetch of row_ptr[d0 .. d0+GC]
    int rpv = row_ptr[min(d0 + lane, n)];

    // hoisted epilogue operands (FINAL only)
    float4 bv = make_float4(0.f, 0.f, 0.f, 0.f);
    float4 b2v = make_float4(0.f, 0.f, 0.f, 0.f);
    int ff = 0;
    if (FINAL) {
        ff = *fflag;
        bv = *(const float4*)(b12 + c);
        if (ff) {
            ushort4 u = *(const ushort4*)((const unsigned short*)b2 + c);
            b2v = make_float4(bsu(u.x), bsu(u.y), bsu(u.z), bsu(u.w));
        } else {
            b2v = *(const float4*)((const float*)b2 + c);
        }
    }

    for (int i = 0; i < GC; ++i) {
        int d = d0 + i;
        if (d >= n) break;
        int beg = __shfl(rpv, i);
        int end = __shfl(rpv, i + 1);
        int deg = end - beg;
        float di = rsqrtf((float)(deg + 1));

        float ax = 0.f, ay = 0.f, az = 0.f, aw = 0.f, wsum = 0.f;
        if (half == 0) {
            float4 s = *(const float4*)(src_feat + (size_t)d * 128 + c);
            ax = di * s.x; ay = di * s.y; az = di * s.z; aw = di * s.w;
        }
        for (int ch = 0; ch < deg; ch += 64) {
            int idx = beg + ch + lane;
            if (idx >= E) idx = E - 1;            // safe over-read, never consumed
            int2 rec = csr[idx];                  // 64 edge records in one instr
            int lim = deg - ch; if (lim > 64) lim = 64;
            for (int t = half; t < lim; t += 2) {
                int srcn = __shfl(rec.x, t);
                float w = __int_as_float(__shfl(rec.y, t));
                float4 v = *(const float4*)(src_feat + (size_t)srcn * 128 + c);
                ax += w * v.x; ay += w * v.y; az += w * v.z; aw += w * v.w;
                wsum += w;
            }
        }
        // combine the two halves (lane i <-> lane i+32)
        ax += __shfl_xor(ax, 32);
        ay += __shfl_xor(ay, 32);
        az += __shfl_xor(az, 32);
        aw += __shfl_xor(aw, 32);
        wsum += __shfl_xor(wsum, 32);
        if (half == 0) {
            ax *= di; ay *= di; az *= di; aw *= di;
            if (!FINAL) {
                *(float4*)(dstf + (size_t)d * 128 + c) = make_float4(ax, ay, az, aw);
            } else {
                float coef = di * (wsum + di);
                float o0 = ax + coef * bv.x + b2v.x;
                float o1 = ay + coef * bv.y + b2v.y;
                float o2 = az + coef * bv.z + b2v.z;
                float o3 = aw + coef * bv.w + b2v.w;
                if (ff) {
                    ushort4 u = make_ushort4((unsigned short)f2bs(o0), (unsigned short)f2bs(o1),
                                             (unsigned short)f2bs(o2), (unsigned short)f2bs(o3));
                    *(ushort4*)((unsigned short*)out + (size_t)d * 128 + c) = u;
                } else {
                    *(float4*)((float*)out + (size_t)d * 128 + c) = make_float4(o0, o1, o2, o3);
                }
            }
        }
    }
}

// ---- diagnostic: workspace too small -> fill out with recognizable sentinel
__global__ __launch_bounds__(256) void k_sentinel(unsigned short* __restrict__ out, int total) {
    int t = blockIdx.x * 256 + threadIdx.x;
    if (t < total) out[t] = 0x4641;              // bf16(12344)
}

extern "C" void kernel_launch(void* const* d_in, const int* in_sizes, int n_in,
                              void* d_out, int out_size, void* d_ws, size_t ws_size,
                              hipStream_t stream) {
    const int n = out_size / DOUT;               // 100000

    // ---- identify inputs by unique flat element counts; positional fallback.
    const void *x = nullptr, *W1 = nullptr, *b1 = nullptr, *W2 = nullptr, *b2 = nullptr;
    const void* ei_raw = nullptr;
    int E = 0;
    const long long nx = (long long)n * DIN;
    for (int i = 0; i < n_in; ++i) {
        long long s = in_sizes[i];
        if      (s == nx && !x)                      x  = d_in[i];
        else if (s == (long long)DIN * DIN && !W1)   W1 = d_in[i];
        else if (s == (long long)DIN && !b1)         b1 = d_in[i];
        else if (s == (long long)DIN * DOUT && !W2)  W2 = d_in[i];
        else if (s == (long long)DOUT && !b2)        b2 = d_in[i];
        else if (s == 1) { /* original_size scalar */ }
        else if (!ei_raw) { ei_raw = d_in[i]; E = (int)(s / 2); }
    }
    if (!x || !W1 || !b1 || !W2 || !b2 || !ei_raw) {   // fallback: documented order
        x  = d_in[0];
        ei_raw = d_in[1];  E = in_sizes[1] / 2;
        W1 = d_in[3]; b1 = d_in[4]; W2 = d_in[5]; b2 = d_in[6];
    }
    if (E < 1) E = 1;

    const int nzb = (n + 255) / 256;             // 391

    // ---- workspace layout
    char* ws = (char*)d_ws;
    size_t off = 0;
    auto alloc = [&](size_t bytes) { void* p = ws + off; off = (off + bytes + 255) & ~255ULL; return p; };
    int*   eflag    = (int*)alloc(4);
    int*   fflag    = (int*)alloc(4);
    int*   degi     = (int*)alloc((size_t)n * 4);
    float* b12      = (float*)alloc(DOUT * 4);
    __hip_bfloat16* w12p = (__hip_bfloat16*)alloc(DIN * DOUT * 2);
    int*   row_ptr  = (int*)alloc(((size_t)n + 1) * 4);
    int*   cursor   = (int*)alloc((size_t)n * 4);
    int*   blocksum = (int*)alloc(512 * 4);
    int2*  csr      = (int2*)alloc((size_t)E * 8);
    float* M        = (float*)alloc((size_t)n * DOUT * 4);   // x@W12 (fp32)
    float* B1       = (float*)alloc((size_t)n * DOUT * 4);   // A·M   (fp32)

    if (ws_size < off) {   // workspace insufficient -> sentinel output, bail
        k_sentinel<<<(out_size + 255) / 256, 256, 0, stream>>>((unsigned short*)d_out, out_size);
        return;
    }

    // ---- zero degi + dtype detection (one kernel)
    k_pre<<<nzb + 2, 256, 0, stream>>>(degi, n, nzb, (const unsigned short*)x, fflag,
                                       (const int*)ei_raw, eflag);

    // ---- weights (+ b12 fused as block 64)
    k_w12<<<65, 256, 0, stream>>>(W1, W2, b1, fflag, w12p, b12);

    // ---- graph preprocessing: degree -> scan -> CSR
    k_deg<<<(E + 255) / 256, 256, 0, stream>>>(ei_raw, eflag, E, degi);
    k_scan1<<<nzb, 256, 0, stream>>>(degi, row_ptr, blocksum, n);
    if (nzb <= 512) {
        k_scan3<<<nzb, 512, 0, stream>>>(row_ptr, cursor, blocksum, nzb, n, E);
    } else {
        k_scan2<<<1, 512, 0, stream>>>(blocksum, nzb);
        k_scan3b<<<nzb, 256, 0, stream>>>(row_ptr, cursor, blocksum, n, E);
    }
    k_fill<<<(E + 255) / 256, 256, 0, stream>>>(ei_raw, eflag, E, degi, cursor, csr);

    // ---- GEMM: M = x @ W12   (64 rows per wave, 1-wave blocks for load balance)
    k_gemm<<<(n + 63) / 64, 64, 0, stream>>>(x, (const short*)w12p, fflag, M, n);

    // ---- two CSR-gather aggregations (second one fuses bias epilogue + store)
    int gwaves = (n + GC - 1) / GC;
    int gb = (gwaves + 3) / 4;
    k_gather<false><<<gb, 256, 0, stream>>>(row_ptr, csr, M, B1,
                                            nullptr, nullptr, fflag, nullptr, n, E);
    k_gather<true><<<gb, 256, 0, stream>>>(row_ptr, csr, B1, nullptr,
                                           b12, b2, fflag, d_out, n, E);
}